// Round 1
// baseline (795.099 us; speedup 1.0000x reference)
//
#include <hip/hip_runtime.h>
#include <math.h>

#define D 2048
#define S_LEN 4096
#define NB 4
#define NTOK (NB * S_LEN)  // 16384

__device__ __forceinline__ float gelu_tanh(float v) {
    const float c = 0.7978845608028654f;
    float t = tanhf(c * (v + 0.044715f * v * v * v));
    return 0.5f * v * (1.0f + t);
}

// ---------------- K0: one-time weight transposes for coalesced per-f loads
// W1 [D][16] -> W1t [16][D] ;  V [D][4] -> Vt [4][D]
__global__ __launch_bounds__(256) void k0_transpose(
        const float* __restrict__ W1, const float* __restrict__ V,
        float* __restrict__ W1t, float* __restrict__ Vt)
{
    const int id = blockIdx.x * 256 + threadIdx.x;
    if (id < D * 16) {
        const int d = id >> 4, f = id & 15;
        W1t[f * D + d] = W1[id];
    } else {
        const int id2 = id - D * 16;          // < D*4
        const int d = id2 >> 2, r = id2 & 3;
        Vt[r * D + d] = V[id2];
    }
}

// ---------------- K1: u[t][r] = rsqrt(mean(x^2)+eps) * sum_d x[d]*nw[d]*V[d][r]
// one wave handles 4 tokens; Vt rows loaded coalesced
__global__ __launch_bounds__(256) void k1_u_kernel(
        const float* __restrict__ x, const float* __restrict__ nw,
        const float* __restrict__ Vt, float* __restrict__ u)
{
    const int gwave = (blockIdx.x * 256 + threadIdx.x) >> 6;
    const int lane  = threadIdx.x & 63;
    const int t0 = gwave * 4;

    float ss[4] = {0.f, 0.f, 0.f, 0.f};
    float uv[4][4] = {};

    #pragma unroll
    for (int j = 0; j < 8; ++j) {
        const int d0 = j * 256 + lane * 4;
        const float4 nw4 = *reinterpret_cast<const float4*>(nw + d0);
        float4 z4[4];
        #pragma unroll
        for (int tk = 0; tk < 4; ++tk) {
            const float4 xv = *reinterpret_cast<const float4*>(x + (size_t)(t0 + tk) * D + d0);
            ss[tk] += xv.x*xv.x + xv.y*xv.y + xv.z*xv.z + xv.w*xv.w;
            z4[tk].x = xv.x*nw4.x; z4[tk].y = xv.y*nw4.y;
            z4[tk].z = xv.z*nw4.z; z4[tk].w = xv.w*nw4.w;
        }
        #pragma unroll
        for (int r = 0; r < 4; ++r) {
            const float4 vv = *reinterpret_cast<const float4*>(Vt + r * D + d0);  // coalesced
            #pragma unroll
            for (int tk = 0; tk < 4; ++tk)
                uv[tk][r] += z4[tk].x*vv.x + z4[tk].y*vv.y + z4[tk].z*vv.z + z4[tk].w*vv.w;
        }
    }
    #pragma unroll
    for (int m = 1; m < 64; m <<= 1) {
        #pragma unroll
        for (int tk = 0; tk < 4; ++tk) {
            ss[tk] += __shfl_xor(ss[tk], m);
            #pragma unroll
            for (int r = 0; r < 4; ++r) uv[tk][r] += __shfl_xor(uv[tk][r], m);
        }
    }
    if (lane < 16) {
        float ssv = ss[0], uvv = uv[0][0];
        #pragma unroll
        for (int tk = 0; tk < 4; ++tk)
            #pragma unroll
            for (int r = 0; r < 4; ++r)
                if (lane == tk * 4 + r) { ssv = ss[tk]; uvv = uv[tk][r]; }
        const float rstd = rsqrtf(ssv * (1.0f / 2048.0f) + 1e-6f);
        u[(size_t)t0 * 4 + lane] = rstd * uvv;  // contiguous 64B store
    }
}

// ---------------- K2: chunked scan  h_t = a*h_{t-1} + u_t  per (b, r) series
__global__ __launch_bounds__(256) void k2_scan_kernel(
        const float* __restrict__ u, const float* __restrict__ a_logit,
        float* __restrict__ hs)
{
    __shared__ float lds[256];
    const int b = blockIdx.x >> 2;
    const int r = blockIdx.x & 3;
    const int i = threadIdx.x;
    const float a = 1.0f / (1.0f + expf(-a_logit[r]));
    const float* up = u  + (size_t)b * S_LEN * 4 + r;
    float*       hp = hs + (size_t)b * S_LEN * 4 + r;

    float ul[16];
    float h = 0.f;
    const int s0 = i * 16;
    #pragma unroll
    for (int k = 0; k < 16; ++k) { ul[k] = up[(size_t)(s0 + k) * 4]; h = a * h + ul[k]; }

    const float a2 = a*a, a4 = a2*a2, a8 = a4*a4;
    float m = a8 * a8;  // a^16
    float run = h;
    lds[i] = run;
    for (int off = 1; off < 256; off <<= 1) {
        __syncthreads();
        const float v = (i >= off) ? lds[i - off] : 0.f;
        __syncthreads();
        run += m * v;
        lds[i] = run;
        m *= m;
    }
    __syncthreads();
    float hh = (i == 0) ? 0.f : lds[i - 1];
    #pragma unroll
    for (int k = 0; k < 16; ++k) { hh = a * hh + ul[k]; hp[(size_t)(s0 + k) * 4] = hh; }
}

// ---------------- K3: fused  x2 = x + hs*U^T ; rms2 ; t = gelu(n2@W1) ; out = x2 + t@W2
// restructured to avoid spills:
//  - W1t per-f coalesced loads (4 transient regs instead of 64)
//  - pf reduction: 2-stage quad shuffle + LDS transpose (no 6-stage 64-wide butterfly)
//  - __launch_bounds__(256,3) pins <=168 VGPR -> 3 waves/SIMD
__global__ __launch_bounds__(256, 3) void k3_fused_kernel(
        const float* __restrict__ x, const float* __restrict__ nw,
        const float* __restrict__ U, const float* __restrict__ hs,
        const float* __restrict__ W1t, const float* __restrict__ W2,
        float* __restrict__ out)
{
    __shared__ float red[4][64][17];   // [wave][value tk*16+f][quad], +1 pad: <=2-way banks
    __shared__ float tvs[4][64];
    const int w = threadIdx.x >> 6;
    const int lane = threadIdx.x & 63;
    const int t0 = (blockIdx.x * 4 + w) * 4;
    const float4* U4  = reinterpret_cast<const float4*>(U);
    const float4* hs4 = reinterpret_cast<const float4*>(hs);
    float4 hv[4];
    #pragma unroll
    for (int tk = 0; tk < 4; ++tk) hv[tk] = hs4[t0 + tk];

    float ss[4] = {0.f, 0.f, 0.f, 0.f};
    float pf[4][16] = {};

    // phase A: ss (rms2) and pf (n2 @ W1) accumulation
    #pragma unroll
    for (int j = 0; j < 8; ++j) {
        const int d0 = j * 256 + lane * 4;
        const float4 nw4 = *reinterpret_cast<const float4*>(nw + d0);
        float4 z4[4];
        {
            float4 ur[4];
            #pragma unroll
            for (int i = 0; i < 4; ++i) ur[i] = U4[d0 + i];
            #pragma unroll
            for (int tk = 0; tk < 4; ++tk) {
                const float4 xv = *reinterpret_cast<const float4*>(x + (size_t)(t0 + tk) * D + d0);
                const float y0 = hv[tk].x*ur[0].x + hv[tk].y*ur[0].y + hv[tk].z*ur[0].z + hv[tk].w*ur[0].w;
                const float y1 = hv[tk].x*ur[1].x + hv[tk].y*ur[1].y + hv[tk].z*ur[1].z + hv[tk].w*ur[1].w;
                const float y2 = hv[tk].x*ur[2].x + hv[tk].y*ur[2].y + hv[tk].z*ur[2].z + hv[tk].w*ur[2].w;
                const float y3 = hv[tk].x*ur[3].x + hv[tk].y*ur[3].y + hv[tk].z*ur[3].z + hv[tk].w*ur[3].w;
                const float x20 = xv.x + y0, x21 = xv.y + y1, x22 = xv.z + y2, x23 = xv.w + y3;
                ss[tk] += x20*x20 + x21*x21 + x22*x22 + x23*x23;
                z4[tk].x = x20*nw4.x; z4[tk].y = x21*nw4.y;
                z4[tk].z = x22*nw4.z; z4[tk].w = x23*nw4.w;
            }
        }
        #pragma unroll
        for (int f = 0; f < 16; ++f) {
            const float4 wv = *reinterpret_cast<const float4*>(W1t + f * D + d0);  // coalesced
            #pragma unroll
            for (int tk = 0; tk < 4; ++tk)
                pf[tk][f] += z4[tk].x*wv.x + z4[tk].y*wv.y + z4[tk].z*wv.z + z4[tk].w*wv.w;
        }
    }

    // ss: small full butterfly (all lanes end with all 4 sums)
    #pragma unroll
    for (int m = 1; m < 64; m <<= 1) {
        #pragma unroll
        for (int tk = 0; tk < 4; ++tk) ss[tk] += __shfl_xor(ss[tk], m);
    }

    // pf: reduce within quads (cheap xor-1/xor-2), then LDS transpose-sum
    #pragma unroll
    for (int tk = 0; tk < 4; ++tk)
        #pragma unroll
        for (int f = 0; f < 16; ++f) {
            pf[tk][f] += __shfl_xor(pf[tk][f], 1);
            pf[tk][f] += __shfl_xor(pf[tk][f], 2);
        }
    {
        // lane l writes value v = (l&3)*16+f (its quad-sum) into column l>>2
        const int q = lane & 3, c = lane >> 2;
        #pragma unroll
        for (int f = 0; f < 16; ++f) {
            float val = pf[0][f];
            if (q == 1) val = pf[1][f];
            if (q == 2) val = pf[2][f];
            if (q == 3) val = pf[3][f];
            red[w][q * 16 + f][c] = val;
        }
    }
    __syncthreads();
    float pfsum = 0.f;
    #pragma unroll
    for (int c = 0; c < 16; ++c) pfsum += red[w][lane][c];  // lane v sums its 16 quad-partials

    const int mytk = lane >> 4;
    float ssv = ss[0];
    if (mytk == 1) ssv = ss[1];
    if (mytk == 2) ssv = ss[2];
    if (mytk == 3) ssv = ss[3];
    const float rstd = rsqrtf(ssv * (1.0f / 2048.0f) + 1e-6f);
    tvs[w][lane] = gelu_tanh(rstd * pfsum);   // lane = tk*16+f
    __syncthreads();

    float tvv[4][16];   // live only in phase C; pf[] is dead here
    #pragma unroll
    for (int tk = 0; tk < 4; ++tk)
        #pragma unroll
        for (int c = 0; c < 4; ++c) {
            const float4 tv4 = *reinterpret_cast<const float4*>(&tvs[w][tk * 16 + c * 4]);
            tvv[tk][c*4+0] = tv4.x; tvv[tk][c*4+1] = tv4.y;
            tvv[tk][c*4+2] = tv4.z; tvv[tk][c*4+3] = tv4.w;
        }

    // phase C: out = x2 + t @ W2  (x2 recomputed; x row is L2/L3-hot from phase A)
    #pragma unroll
    for (int j = 0; j < 8; ++j) {
        const int d0 = j * 256 + lane * 4;
        float4 ur[4];
        #pragma unroll
        for (int i = 0; i < 4; ++i) ur[i] = U4[d0 + i];
        float4 acc[4];
        #pragma unroll
        for (int tk = 0; tk < 4; ++tk) {
            const float4 xv = *reinterpret_cast<const float4*>(x + (size_t)(t0 + tk) * D + d0);
            acc[tk].x = xv.x + hv[tk].x*ur[0].x + hv[tk].y*ur[0].y + hv[tk].z*ur[0].z + hv[tk].w*ur[0].w;
            acc[tk].y = xv.y + hv[tk].x*ur[1].x + hv[tk].y*ur[1].y + hv[tk].z*ur[1].z + hv[tk].w*ur[1].w;
            acc[tk].z = xv.z + hv[tk].x*ur[2].x + hv[tk].y*ur[2].y + hv[tk].z*ur[2].z + hv[tk].w*ur[2].w;
            acc[tk].w = xv.w + hv[tk].x*ur[3].x + hv[tk].y*ur[3].y + hv[tk].z*ur[3].z + hv[tk].w*ur[3].w;
        }
        #pragma unroll
        for (int f = 0; f < 16; ++f) {
            const float4 w2v = *reinterpret_cast<const float4*>(W2 + (size_t)f * D + d0);
            #pragma unroll
            for (int tk = 0; tk < 4; ++tk) {
                acc[tk].x += tvv[tk][f] * w2v.x;
                acc[tk].y += tvv[tk][f] * w2v.y;
                acc[tk].z += tvv[tk][f] * w2v.z;
                acc[tk].w += tvv[tk][f] * w2v.w;
            }
        }
        #pragma unroll
        for (int tk = 0; tk < 4; ++tk)
            *reinterpret_cast<float4*>(out + (size_t)(t0 + tk) * D + d0) = acc[tk];
    }
}

extern "C" void kernel_launch(void* const* d_in, const int* in_sizes, int n_in,
                              void* d_out, int out_size, void* d_ws, size_t ws_size,
                              hipStream_t stream)
{
    (void)in_sizes; (void)n_in; (void)out_size; (void)ws_size;
    const float* x  = (const float*)d_in[0];
    const float* nw = (const float*)d_in[1];
    const float* V  = (const float*)d_in[2];
    const float* U  = (const float*)d_in[3];
    const float* al = (const float*)d_in[4];
    const float* W1 = (const float*)d_in[5];
    const float* W2 = (const float*)d_in[6];
    float* out = (float*)d_out;
    float* u   = (float*)d_ws;                 // [NTOK][4]
    float* hs  = u + (size_t)NTOK * 4;         // [NTOK][4]
    float* W1t = hs + (size_t)NTOK * 4;        // [16][D]
    float* Vt  = W1t + (size_t)16 * D;         // [4][D]
    // total workspace: 172032 floats = 688 KB

    k0_transpose  <<<dim3(160),       dim3(256), 0, stream>>>(W1, V, W1t, Vt);
    k1_u_kernel   <<<dim3(NTOK / 16), dim3(256), 0, stream>>>(x, nw, Vt, u);
    k2_scan_kernel<<<dim3(16),        dim3(256), 0, stream>>>(u, al, hs);
    k3_fused_kernel<<<dim3(NTOK / 16), dim3(256), 0, stream>>>(x, nw, U, hs, W1t, W2, out);
}

// Round 2
// 571.585 us; speedup vs baseline: 1.3910x; 1.3910x over previous
//
#include <hip/hip_runtime.h>
#include <math.h>

#define D 2048
#define S_LEN 4096
#define NB 4
#define NTOK (NB * S_LEN)  // 16384

__device__ __forceinline__ float gelu_tanh(float v) {
    const float c = 0.7978845608028654f;
    float t = tanhf(c * (v + 0.044715f * v * v * v));
    return 0.5f * v * (1.0f + t);
}

// ---------------- K0: one-time weight transposes for coalesced per-f loads
// W1 [D][16] -> W1t [16][D] ;  V [D][4] -> Vt [4][D]
__global__ __launch_bounds__(256) void k0_transpose(
        const float* __restrict__ W1, const float* __restrict__ V,
        float* __restrict__ W1t, float* __restrict__ Vt)
{
    const int id = blockIdx.x * 256 + threadIdx.x;
    if (id < D * 16) {
        const int d = id >> 4, f = id & 15;
        W1t[f * D + d] = W1[id];
    } else {
        const int id2 = id - D * 16;          // < D*4
        const int d = id2 >> 2, r = id2 & 3;
        Vt[r * D + d] = V[id2];
    }
}

// ---------------- K1: u[t][r] = rsqrt(mean(x^2)+eps) * sum_d x[d]*nw[d]*V[d][r]
// one wave handles 4 tokens; Vt rows loaded coalesced
__global__ __launch_bounds__(256) void k1_u_kernel(
        const float* __restrict__ x, const float* __restrict__ nw,
        const float* __restrict__ Vt, float* __restrict__ u)
{
    const int gwave = (blockIdx.x * 256 + threadIdx.x) >> 6;
    const int lane  = threadIdx.x & 63;
    const int t0 = gwave * 4;

    float ss[4] = {0.f, 0.f, 0.f, 0.f};
    float uv[4][4] = {};

    #pragma unroll
    for (int j = 0; j < 8; ++j) {
        const int d0 = j * 256 + lane * 4;
        const float4 nw4 = *reinterpret_cast<const float4*>(nw + d0);
        float4 z4[4];
        #pragma unroll
        for (int tk = 0; tk < 4; ++tk) {
            const float4 xv = *reinterpret_cast<const float4*>(x + (size_t)(t0 + tk) * D + d0);
            ss[tk] += xv.x*xv.x + xv.y*xv.y + xv.z*xv.z + xv.w*xv.w;
            z4[tk].x = xv.x*nw4.x; z4[tk].y = xv.y*nw4.y;
            z4[tk].z = xv.z*nw4.z; z4[tk].w = xv.w*nw4.w;
        }
        #pragma unroll
        for (int r = 0; r < 4; ++r) {
            const float4 vv = *reinterpret_cast<const float4*>(Vt + r * D + d0);  // coalesced
            #pragma unroll
            for (int tk = 0; tk < 4; ++tk)
                uv[tk][r] += z4[tk].x*vv.x + z4[tk].y*vv.y + z4[tk].z*vv.z + z4[tk].w*vv.w;
        }
    }
    #pragma unroll
    for (int m = 1; m < 64; m <<= 1) {
        #pragma unroll
        for (int tk = 0; tk < 4; ++tk) {
            ss[tk] += __shfl_xor(ss[tk], m);
            #pragma unroll
            for (int r = 0; r < 4; ++r) uv[tk][r] += __shfl_xor(uv[tk][r], m);
        }
    }
    if (lane < 16) {
        float ssv = ss[0], uvv = uv[0][0];
        #pragma unroll
        for (int tk = 0; tk < 4; ++tk)
            #pragma unroll
            for (int r = 0; r < 4; ++r)
                if (lane == tk * 4 + r) { ssv = ss[tk]; uvv = uv[tk][r]; }
        const float rstd = rsqrtf(ssv * (1.0f / 2048.0f) + 1e-6f);
        u[(size_t)t0 * 4 + lane] = rstd * uvv;  // contiguous 64B store
    }
}

// ---------------- K2: chunked scan  h_t = a*h_{t-1} + u_t  per (b, r) series
__global__ __launch_bounds__(256) void k2_scan_kernel(
        const float* __restrict__ u, const float* __restrict__ a_logit,
        float* __restrict__ hs)
{
    __shared__ float lds[256];
    const int b = blockIdx.x >> 2;
    const int r = blockIdx.x & 3;
    const int i = threadIdx.x;
    const float a = 1.0f / (1.0f + expf(-a_logit[r]));
    const float* up = u  + (size_t)b * S_LEN * 4 + r;
    float*       hp = hs + (size_t)b * S_LEN * 4 + r;

    float ul[16];
    float h = 0.f;
    const int s0 = i * 16;
    #pragma unroll
    for (int k = 0; k < 16; ++k) { ul[k] = up[(size_t)(s0 + k) * 4]; h = a * h + ul[k]; }

    const float a2 = a*a, a4 = a2*a2, a8 = a4*a4;
    float m = a8 * a8;  // a^16
    float run = h;
    lds[i] = run;
    for (int off = 1; off < 256; off <<= 1) {
        __syncthreads();
        const float v = (i >= off) ? lds[i - off] : 0.f;
        __syncthreads();
        run += m * v;
        lds[i] = run;
        m *= m;
    }
    __syncthreads();
    float hh = (i == 0) ? 0.f : lds[i - 1];
    #pragma unroll
    for (int k = 0; k < 16; ++k) { hh = a * hh + ul[k]; hp[(size_t)(s0 + k) * 4] = hh; }
}

// ---------------- K3: fused  x2 = x + hs*U^T ; rms2 ; t = gelu(n2@W1) ; out = x2 + t@W2
// round-0 skeleton (full butterfly, small reds LDS, plain launch_bounds) with ONE change:
// W1t per-f coalesced transient loads instead of the resident w1r[4][4] block (-64 regs).
__global__ __launch_bounds__(256) void k3_fused_kernel(
        const float* __restrict__ x, const float* __restrict__ nw,
        const float* __restrict__ U, const float* __restrict__ hs,
        const float* __restrict__ W1t, const float* __restrict__ W2,
        float* __restrict__ out)
{
    __shared__ float reds[4][4][20];
    __shared__ float tvs[4][64];
    const int w = threadIdx.x >> 6;
    const int lane = threadIdx.x & 63;
    const int gwave = blockIdx.x * 4 + w;
    const int t0 = gwave * 4;
    const float4* U4  = reinterpret_cast<const float4*>(U);
    const float4* hs4 = reinterpret_cast<const float4*>(hs);
    float4 hv[4];
    #pragma unroll
    for (int tk = 0; tk < 4; ++tk) hv[tk] = hs4[t0 + tk];

    float ss[4] = {0.f, 0.f, 0.f, 0.f};
    float pf[4][16] = {};

    // phase A: ss (rms2) and pf (n2 @ W1) accumulation
    #pragma unroll
    for (int j = 0; j < 8; ++j) {
        const int d0 = j * 256 + lane * 4;
        const float4 nw4 = *reinterpret_cast<const float4*>(nw + d0);
        float4 z4[4];
        {
            float4 ur[4];
            #pragma unroll
            for (int i = 0; i < 4; ++i) ur[i] = U4[d0 + i];
            #pragma unroll
            for (int tk = 0; tk < 4; ++tk) {
                const float4 xv = *reinterpret_cast<const float4*>(x + (size_t)(t0 + tk) * D + d0);
                const float y0 = hv[tk].x*ur[0].x + hv[tk].y*ur[0].y + hv[tk].z*ur[0].z + hv[tk].w*ur[0].w;
                const float y1 = hv[tk].x*ur[1].x + hv[tk].y*ur[1].y + hv[tk].z*ur[1].z + hv[tk].w*ur[1].w;
                const float y2 = hv[tk].x*ur[2].x + hv[tk].y*ur[2].y + hv[tk].z*ur[2].z + hv[tk].w*ur[2].w;
                const float y3 = hv[tk].x*ur[3].x + hv[tk].y*ur[3].y + hv[tk].z*ur[3].z + hv[tk].w*ur[3].w;
                const float x20 = xv.x + y0, x21 = xv.y + y1, x22 = xv.z + y2, x23 = xv.w + y3;
                ss[tk] += x20*x20 + x21*x21 + x22*x22 + x23*x23;
                z4[tk].x = x20*nw4.x; z4[tk].y = x21*nw4.y;
                z4[tk].z = x22*nw4.z; z4[tk].w = x23*nw4.w;
            }
        }
        #pragma unroll
        for (int f = 0; f < 16; ++f) {
            const float4 wv = *reinterpret_cast<const float4*>(W1t + f * D + d0);  // coalesced
            #pragma unroll
            for (int tk = 0; tk < 4; ++tk)
                pf[tk][f] += z4[tk].x*wv.x + z4[tk].y*wv.y + z4[tk].z*wv.z + z4[tk].w*wv.w;
        }
    }

    // in-wave butterfly reduction (all lanes end with identical full sums) — round-0 codegen
    #pragma unroll
    for (int m = 1; m < 64; m <<= 1) {
        #pragma unroll
        for (int tk = 0; tk < 4; ++tk) {
            ss[tk] += __shfl_xor(ss[tk], m);
            #pragma unroll
            for (int f = 0; f < 16; ++f) pf[tk][f] += __shfl_xor(pf[tk][f], m);
        }
    }
    if (lane == 0) {
        #pragma unroll
        for (int tk = 0; tk < 4; ++tk) {
            reds[w][tk][16] = ss[tk];
            #pragma unroll
            for (int f = 0; f < 16; ++f) reds[w][tk][f] = pf[tk][f];
        }
    }
    __syncthreads();
    {
        const int mytk = lane >> 4, myf = lane & 15;  // 64 lanes = 4 tokens x 16 f: one gelu each
        const float rstd = rsqrtf(reds[w][mytk][16] * (1.0f / 2048.0f) + 1e-6f);
        tvs[w][lane] = gelu_tanh(rstd * reds[w][mytk][myf]);
    }
    __syncthreads();
    float tvv[4][16];
    #pragma unroll
    for (int tk = 0; tk < 4; ++tk)
        #pragma unroll
        for (int f = 0; f < 16; ++f) tvv[tk][f] = tvs[w][tk * 16 + f];

    // phase C: out = x2 + t @ W2  (x2 recomputed; x row is L2/L3-hot from phase A)
    #pragma unroll
    for (int j = 0; j < 8; ++j) {
        const int d0 = j * 256 + lane * 4;
        float4 ur[4];
        #pragma unroll
        for (int i = 0; i < 4; ++i) ur[i] = U4[d0 + i];
        float4 acc[4];
        #pragma unroll
        for (int tk = 0; tk < 4; ++tk) {
            const float4 xv = *reinterpret_cast<const float4*>(x + (size_t)(t0 + tk) * D + d0);
            acc[tk].x = xv.x + hv[tk].x*ur[0].x + hv[tk].y*ur[0].y + hv[tk].z*ur[0].z + hv[tk].w*ur[0].w;
            acc[tk].y = xv.y + hv[tk].x*ur[1].x + hv[tk].y*ur[1].y + hv[tk].z*ur[1].z + hv[tk].w*ur[1].w;
            acc[tk].z = xv.z + hv[tk].x*ur[2].x + hv[tk].y*ur[2].y + hv[tk].z*ur[2].z + hv[tk].w*ur[2].w;
            acc[tk].w = xv.w + hv[tk].x*ur[3].x + hv[tk].y*ur[3].y + hv[tk].z*ur[3].z + hv[tk].w*ur[3].w;
        }
        #pragma unroll
        for (int f = 0; f < 16; ++f) {
            const float4 w2v = *reinterpret_cast<const float4*>(W2 + (size_t)f * D + d0);
            #pragma unroll
            for (int tk = 0; tk < 4; ++tk) {
                acc[tk].x += tvv[tk][f] * w2v.x;
                acc[tk].y += tvv[tk][f] * w2v.y;
                acc[tk].z += tvv[tk][f] * w2v.z;
                acc[tk].w += tvv[tk][f] * w2v.w;
            }
        }
        #pragma unroll
        for (int tk = 0; tk < 4; ++tk)
            *reinterpret_cast<float4*>(out + (size_t)(t0 + tk) * D + d0) = acc[tk];
    }
}

extern "C" void kernel_launch(void* const* d_in, const int* in_sizes, int n_in,
                              void* d_out, int out_size, void* d_ws, size_t ws_size,
                              hipStream_t stream)
{
    (void)in_sizes; (void)n_in; (void)out_size; (void)ws_size;
    const float* x  = (const float*)d_in[0];
    const float* nw = (const float*)d_in[1];
    const float* V  = (const float*)d_in[2];
    const float* U  = (const float*)d_in[3];
    const float* al = (const float*)d_in[4];
    const float* W1 = (const float*)d_in[5];
    const float* W2 = (const float*)d_in[6];
    float* out = (float*)d_out;
    float* u   = (float*)d_ws;                 // [NTOK][4]
    float* hs  = u + (size_t)NTOK * 4;         // [NTOK][4]
    float* W1t = hs + (size_t)NTOK * 4;        // [16][D]
    float* Vt  = W1t + (size_t)16 * D;         // [4][D]
    // total workspace: 172032 floats = 688 KB

    k0_transpose  <<<dim3(160),       dim3(256), 0, stream>>>(W1, V, W1t, Vt);
    k1_u_kernel   <<<dim3(NTOK / 16), dim3(256), 0, stream>>>(x, nw, Vt, u);
    k2_scan_kernel<<<dim3(16),        dim3(256), 0, stream>>>(u, al, hs);
    k3_fused_kernel<<<dim3(NTOK / 16), dim3(256), 0, stream>>>(x, nw, U, hs, W1t, W2, out);
}

// Round 3
// 462.418 us; speedup vs baseline: 1.7194x; 1.2361x over previous
//
#include <hip/hip_runtime.h>
#include <math.h>

#define D 2048
#define S_LEN 4096
#define NB 4
#define NTOK (NB * S_LEN)  // 16384

__device__ __forceinline__ float gelu_tanh(float v) {
    const float c = 0.7978845608028654f;
    float t = tanhf(c * (v + 0.044715f * v * v * v));
    return 0.5f * v * (1.0f + t);
}

// ---------------- K0: one-time weight transposes for coalesced per-f loads
// W1 [D][16] -> W1t [16][D] ;  V [D][4] -> Vt [4][D]
__global__ __launch_bounds__(256) void k0_transpose(
        const float* __restrict__ W1, const float* __restrict__ V,
        float* __restrict__ W1t, float* __restrict__ Vt)
{
    const int id = blockIdx.x * 256 + threadIdx.x;
    if (id < D * 16) {
        const int d = id >> 4, f = id & 15;
        W1t[f * D + d] = W1[id];
    } else {
        const int id2 = id - D * 16;          // < D*4
        const int d = id2 >> 2, r = id2 & 3;
        Vt[r * D + d] = V[id2];
    }
}

// ---------------- K1: u[t][r] = rsqrt(mean(x^2)+eps) * sum_d x[d]*nw[d]*V[d][r]
// one wave handles 4 tokens; Vt rows loaded coalesced
__global__ __launch_bounds__(256) void k1_u_kernel(
        const float* __restrict__ x, const float* __restrict__ nw,
        const float* __restrict__ Vt, float* __restrict__ u)
{
    const int gwave = (blockIdx.x * 256 + threadIdx.x) >> 6;
    const int lane  = threadIdx.x & 63;
    const int t0 = gwave * 4;

    float ss[4] = {0.f, 0.f, 0.f, 0.f};
    float uv[4][4] = {};

    #pragma unroll
    for (int j = 0; j < 8; ++j) {
        const int d0 = j * 256 + lane * 4;
        const float4 nw4 = *reinterpret_cast<const float4*>(nw + d0);
        float4 z4[4];
        #pragma unroll
        for (int tk = 0; tk < 4; ++tk) {
            const float4 xv = *reinterpret_cast<const float4*>(x + (size_t)(t0 + tk) * D + d0);
            ss[tk] += xv.x*xv.x + xv.y*xv.y + xv.z*xv.z + xv.w*xv.w;
            z4[tk].x = xv.x*nw4.x; z4[tk].y = xv.y*nw4.y;
            z4[tk].z = xv.z*nw4.z; z4[tk].w = xv.w*nw4.w;
        }
        #pragma unroll
        for (int r = 0; r < 4; ++r) {
            const float4 vv = *reinterpret_cast<const float4*>(Vt + r * D + d0);  // coalesced
            #pragma unroll
            for (int tk = 0; tk < 4; ++tk)
                uv[tk][r] += z4[tk].x*vv.x + z4[tk].y*vv.y + z4[tk].z*vv.z + z4[tk].w*vv.w;
        }
    }
    #pragma unroll
    for (int m = 1; m < 64; m <<= 1) {
        #pragma unroll
        for (int tk = 0; tk < 4; ++tk) {
            ss[tk] += __shfl_xor(ss[tk], m);
            #pragma unroll
            for (int r = 0; r < 4; ++r) uv[tk][r] += __shfl_xor(uv[tk][r], m);
        }
    }
    if (lane < 16) {
        float ssv = ss[0], uvv = uv[0][0];
        #pragma unroll
        for (int tk = 0; tk < 4; ++tk)
            #pragma unroll
            for (int r = 0; r < 4; ++r)
                if (lane == tk * 4 + r) { ssv = ss[tk]; uvv = uv[tk][r]; }
        const float rstd = rsqrtf(ssv * (1.0f / 2048.0f) + 1e-6f);
        u[(size_t)t0 * 4 + lane] = rstd * uvv;  // contiguous 64B store
    }
}

// ---------------- K2: chunked scan  h_t = a*h_{t-1} + u_t  per (b, r) series
__global__ __launch_bounds__(256) void k2_scan_kernel(
        const float* __restrict__ u, const float* __restrict__ a_logit,
        float* __restrict__ hs)
{
    __shared__ float lds[256];
    const int b = blockIdx.x >> 2;
    const int r = blockIdx.x & 3;
    const int i = threadIdx.x;
    const float a = 1.0f / (1.0f + expf(-a_logit[r]));
    const float* up = u  + (size_t)b * S_LEN * 4 + r;
    float*       hp = hs + (size_t)b * S_LEN * 4 + r;

    float ul[16];
    float h = 0.f;
    const int s0 = i * 16;
    #pragma unroll
    for (int k = 0; k < 16; ++k) { ul[k] = up[(size_t)(s0 + k) * 4]; h = a * h + ul[k]; }

    const float a2 = a*a, a4 = a2*a2, a8 = a4*a4;
    float m = a8 * a8;  // a^16
    float run = h;
    lds[i] = run;
    for (int off = 1; off < 256; off <<= 1) {
        __syncthreads();
        const float v = (i >= off) ? lds[i - off] : 0.f;
        __syncthreads();
        run += m * v;
        lds[i] = run;
        m *= m;
    }
    __syncthreads();
    float hh = (i == 0) ? 0.f : lds[i - 1];
    #pragma unroll
    for (int k = 0; k < 16; ++k) { hh = a * hh + ul[k]; hp[(size_t)(s0 + k) * 4] = hh; }
}

// ---------------- K3: fused  x2 = x + hs*U^T ; rms2 ; t = gelu(n2@W1) ; out = x2 + t@W2
// 2 tokens/wave: pf[2][16]=32 accumulator regs (was 64) -> peak live well under 256, no scratch.
// Weight rows (U, W1t, W2) are L2-resident (~300 KB working set); the 2x re-read is L2 traffic only.
__global__ __launch_bounds__(256) void k3_fused_kernel(
        const float* __restrict__ x, const float* __restrict__ nw,
        const float* __restrict__ U, const float* __restrict__ hs,
        const float* __restrict__ W1t, const float* __restrict__ W2,
        float* __restrict__ out)
{
    __shared__ float reds[4][2][20];
    __shared__ float tvs[4][32];
    const int w = threadIdx.x >> 6;
    const int lane = threadIdx.x & 63;
    const int gwave = blockIdx.x * 4 + w;
    const int t0 = gwave * 2;                    // 2 tokens per wave
    const float4* U4  = reinterpret_cast<const float4*>(U);
    const float4* hs4 = reinterpret_cast<const float4*>(hs);
    float4 hv[2];
    #pragma unroll
    for (int tk = 0; tk < 2; ++tk) hv[tk] = hs4[t0 + tk];

    float ss[2] = {0.f, 0.f};
    float pf[2][16] = {};

    // phase A: ss (rms2) and pf (n2 @ W1) accumulation
    #pragma unroll
    for (int j = 0; j < 8; ++j) {
        const int d0 = j * 256 + lane * 4;
        const float4 nw4 = *reinterpret_cast<const float4*>(nw + d0);
        float4 z4[2];
        {
            float4 ur[4];
            #pragma unroll
            for (int i = 0; i < 4; ++i) ur[i] = U4[d0 + i];
            #pragma unroll
            for (int tk = 0; tk < 2; ++tk) {
                const float4 xv = *reinterpret_cast<const float4*>(x + (size_t)(t0 + tk) * D + d0);
                const float y0 = hv[tk].x*ur[0].x + hv[tk].y*ur[0].y + hv[tk].z*ur[0].z + hv[tk].w*ur[0].w;
                const float y1 = hv[tk].x*ur[1].x + hv[tk].y*ur[1].y + hv[tk].z*ur[1].z + hv[tk].w*ur[1].w;
                const float y2 = hv[tk].x*ur[2].x + hv[tk].y*ur[2].y + hv[tk].z*ur[2].z + hv[tk].w*ur[2].w;
                const float y3 = hv[tk].x*ur[3].x + hv[tk].y*ur[3].y + hv[tk].z*ur[3].z + hv[tk].w*ur[3].w;
                const float x20 = xv.x + y0, x21 = xv.y + y1, x22 = xv.z + y2, x23 = xv.w + y3;
                ss[tk] += x20*x20 + x21*x21 + x22*x22 + x23*x23;
                z4[tk].x = x20*nw4.x; z4[tk].y = x21*nw4.y;
                z4[tk].z = x22*nw4.z; z4[tk].w = x23*nw4.w;
            }
        }
        #pragma unroll
        for (int f = 0; f < 16; ++f) {
            const float4 wv = *reinterpret_cast<const float4*>(W1t + f * D + d0);  // coalesced
            #pragma unroll
            for (int tk = 0; tk < 2; ++tk)
                pf[tk][f] += z4[tk].x*wv.x + z4[tk].y*wv.y + z4[tk].z*wv.z + z4[tk].w*wv.w;
        }
    }

    // in-wave butterfly reduction over 34 values (all lanes end with full sums)
    #pragma unroll
    for (int m = 1; m < 64; m <<= 1) {
        #pragma unroll
        for (int tk = 0; tk < 2; ++tk) {
            ss[tk] += __shfl_xor(ss[tk], m);
            #pragma unroll
            for (int f = 0; f < 16; ++f) pf[tk][f] += __shfl_xor(pf[tk][f], m);
        }
    }
    if (lane == 0) {
        #pragma unroll
        for (int tk = 0; tk < 2; ++tk) {
            reds[w][tk][16] = ss[tk];
            #pragma unroll
            for (int f = 0; f < 16; ++f) reds[w][tk][f] = pf[tk][f];
        }
    }
    __syncthreads();
    if (lane < 32) {
        const int mytk = lane >> 4, myf = lane & 15;  // 32 lanes = 2 tokens x 16 f
        const float rstd = rsqrtf(reds[w][mytk][16] * (1.0f / 2048.0f) + 1e-6f);
        tvs[w][lane] = gelu_tanh(rstd * reds[w][mytk][myf]);
    }
    __syncthreads();
    float tvv[2][16];   // live only in phase C; pf[] is dead here
    #pragma unroll
    for (int tk = 0; tk < 2; ++tk)
        #pragma unroll
        for (int f = 0; f < 16; ++f) tvv[tk][f] = tvs[w][tk * 16 + f];

    // phase C: out = x2 + t @ W2  (x2 recomputed; x row is L2-hot from phase A)
    #pragma unroll
    for (int j = 0; j < 8; ++j) {
        const int d0 = j * 256 + lane * 4;
        float4 ur[4];
        #pragma unroll
        for (int i = 0; i < 4; ++i) ur[i] = U4[d0 + i];
        float4 acc[2];
        #pragma unroll
        for (int tk = 0; tk < 2; ++tk) {
            const float4 xv = *reinterpret_cast<const float4*>(x + (size_t)(t0 + tk) * D + d0);
            acc[tk].x = xv.x + hv[tk].x*ur[0].x + hv[tk].y*ur[0].y + hv[tk].z*ur[0].z + hv[tk].w*ur[0].w;
            acc[tk].y = xv.y + hv[tk].x*ur[1].x + hv[tk].y*ur[1].y + hv[tk].z*ur[1].z + hv[tk].w*ur[1].w;
            acc[tk].z = xv.z + hv[tk].x*ur[2].x + hv[tk].y*ur[2].y + hv[tk].z*ur[2].z + hv[tk].w*ur[2].w;
            acc[tk].w = xv.w + hv[tk].x*ur[3].x + hv[tk].y*ur[3].y + hv[tk].z*ur[3].z + hv[tk].w*ur[3].w;
        }
        #pragma unroll
        for (int f = 0; f < 16; ++f) {
            const float4 w2v = *reinterpret_cast<const float4*>(W2 + (size_t)f * D + d0);
            #pragma unroll
            for (int tk = 0; tk < 2; ++tk) {
                acc[tk].x += tvv[tk][f] * w2v.x;
                acc[tk].y += tvv[tk][f] * w2v.y;
                acc[tk].z += tvv[tk][f] * w2v.z;
                acc[tk].w += tvv[tk][f] * w2v.w;
            }
        }
        #pragma unroll
        for (int tk = 0; tk < 2; ++tk)
            *reinterpret_cast<float4*>(out + (size_t)(t0 + tk) * D + d0) = acc[tk];
    }
}

extern "C" void kernel_launch(void* const* d_in, const int* in_sizes, int n_in,
                              void* d_out, int out_size, void* d_ws, size_t ws_size,
                              hipStream_t stream)
{
    (void)in_sizes; (void)n_in; (void)out_size; (void)ws_size;
    const float* x  = (const float*)d_in[0];
    const float* nw = (const float*)d_in[1];
    const float* V  = (const float*)d_in[2];
    const float* U  = (const float*)d_in[3];
    const float* al = (const float*)d_in[4];
    const float* W1 = (const float*)d_in[5];
    const float* W2 = (const float*)d_in[6];
    float* out = (float*)d_out;
    float* u   = (float*)d_ws;                 // [NTOK][4]
    float* hs  = u + (size_t)NTOK * 4;         // [NTOK][4]
    float* W1t = hs + (size_t)NTOK * 4;        // [16][D]
    float* Vt  = W1t + (size_t)16 * D;         // [4][D]
    // total workspace: 172032 floats = 688 KB

    k0_transpose  <<<dim3(160),       dim3(256), 0, stream>>>(W1, V, W1t, Vt);
    k1_u_kernel   <<<dim3(NTOK / 16), dim3(256), 0, stream>>>(x, nw, Vt, u);
    k2_scan_kernel<<<dim3(16),        dim3(256), 0, stream>>>(u, al, hs);
    k3_fused_kernel<<<dim3(NTOK / 8), dim3(256), 0, stream>>>(x, nw, U, hs, W1t, W2, out);
}